// Round 12
// baseline (317.887 us; speedup 1.0000x reference)
//
#include <hip/hip_runtime.h>
#include <stdint.h>

#define D 64
#define KTOT 43744            // C(64,1)+C(64,2)+C(64,3); 43744 = 32*1367
#define NPAIR 2016
#define NOUT 512
#define MROWS 4096
#define BM 128
#define BN 256
#define BK 32
#define NSTEPS (KTOT / BK)    // 1367, exact
#define K2B (KTOT * 2)        // Wt row bytes = 87488

typedef __attribute__((ext_vector_type(8))) short short8;
typedef __attribute__((ext_vector_type(4))) float f32x4;
typedef __attribute__((ext_vector_type(4))) uint32_t u32x4;

__device__ __forceinline__ uint32_t cvtpk(float lo, float hi) {
  uint32_t r;
  asm("v_cvt_pk_bf16_f32 %0, %1, %2" : "=v"(r) : "v"(lo), "v"(hi));
  return r;
}

// unrank k -> (i,j,l); sentinel 64 for unused factors. k < KTOT.
__device__ __forceinline__ void unrank(int k, int& i, int& j, int& l) {
  if (k < D) {
    i = k; j = D; l = D;
  } else if (k < D + NPAIR) {
    int p = k - D;
    i = 0;
    while (p >= D - 1 - i) { p -= D - 1 - i; ++i; }
    j = i + 1 + p; l = D;
  } else {
    int t = k - (D + NPAIR);
    i = 0;
    for (;;) { int c = (D - 1 - i) * (D - 2 - i) / 2; if (t < c) break; t -= c; ++i; }
    j = i + 1;
    while (t >= D - 1 - j) { t -= D - 1 - j; ++j; }
    l = j + 1 + t;
  }
}

__device__ __forceinline__ bool inc_idx(int& i, int& j, int& l) {
  if (l >= D) {
    if (j >= D) { ++i; if (i == D) { i = 0; j = 1; } return true; }
    ++j;
    if (j == D) { ++i; j = i + 1; if (j == D) { i = 0; j = 1; l = 2; } }
    return true;
  }
  ++l;
  if (l == D) {
    ++j; l = j + 1;
    if (l == D) { ++i; j = i + 1; l = j + 1; }
    return true;
  }
  return false;
}

// ---------------- kernel 1: idx table ----------------
__global__ void build_idx_k(uint32_t* __restrict__ idx) {
  int k = blockIdx.x * 256 + threadIdx.x;
  if (k >= KTOT) return;
  int i, j, l;
  unrank(k, i, j, l);
  idx[k] = (uint32_t)i | ((uint32_t)j << 8) | ((uint32_t)l << 16);
}

// ---------------- kernel 2: W [KTOT][512] fp32 -> Wt [512][KTOT] bf16, PLAIN row-major ----------------
// (no bake-swizzle: B-fragments are loaded straight to registers now, no LDS banks involved)
__global__ void wtrans_k(const float* __restrict__ W, char* __restrict__ Wt) {
  __shared__ float tile[64][65];
  int bk = blockIdx.x;          // 64-k tile (0..683)
  int bn = blockIdx.y;          // n tile (0..7)
  int t = threadIdx.x;          // 256
  int k0 = bk * 64, n0 = bn * 64;
  int col = t & 63, r0 = t >> 6;
  #pragma unroll
  for (int p = 0; p < 16; ++p) {
    int row = p * 4 + r0;
    tile[col][row] = (k0 + row < KTOT) ? W[(size_t)(k0 + row) * NOUT + (n0 + col)] : 0.0f;
  }
  __syncthreads();
  for (int u = t; u < 512; u += 256) {
    int n = u >> 3, s8 = u & 7;           // s8: 16B slot within 128B (64 k)
    int kc0 = k0 + s8 * 8;
    if (kc0 >= KTOT) continue;
    int ng = n0 + n;
    int b = s8 * 8;
    u32x4 v = {cvtpk(tile[n][b + 0], tile[n][b + 1]),
               cvtpk(tile[n][b + 2], tile[n][b + 3]),
               cvtpk(tile[n][b + 4], tile[n][b + 5]),
               cvtpk(tile[n][b + 6], tile[n][b + 7])};
    *(u32x4*)(Wt + (size_t)ng * K2B + (size_t)kc0 * 2) = v;
  }
}

// ---------------- kernel 3: fused feature-gen + bf16 MFMA GEMM ----------------
// BM=128 x BN=256, BK=32, 8 waves (2x4 of 64x64 wave tiles), split-K.
// A: LDS double-buffer (swizzled). B: DIRECT global->register frags (L2-resident Wt).
// LDS 48KB; target 2 blocks/CU (16 waves, VGPR+AGPR <= 128/wave).
template<int USE_WT, int USE_IDX>
__global__ void __launch_bounds__(512, 4)
gemm_k(const float* __restrict__ x, const float* __restrict__ W,
       const char* __restrict__ Wt, const uint32_t* __restrict__ idxg,
       float* __restrict__ part, int S, int Slog, int steps_per, int swz) {
  __shared__ float XmT[D * 128];                       // 32KB [i][m] transposed x tile
  __shared__ __align__(16) char Al[2][BM * 64];        // 2x8KB feats bf16, slot ^= (row>>1)&3

  const int t = threadIdx.x;
  const int lane = t & 63;
  const int w = t >> 6;               // wave 0..7

  int mb, ns;
  if (swz) {                          // group same-(nb,sb) mb-blocks on one XCD
    int xcd = blockIdx.x & 7;
    int sub = blockIdx.x >> 3;
    ns = xcd + 8 * (sub >> 5);
    mb = sub & 31;
  } else {
    mb = blockIdx.x & 31;
    ns = blockIdx.x >> 5;
  }
  const int nb = ns >> Slog;
  const int sb = ns & (S - 1);

  // ---- x block rows -> LDS transposed ----
  {
    int m = t >> 2, i0 = (t & 3) * 16;
    const float* src = x + (size_t)(mb * BM + m) * D + i0;
    #pragma unroll
    for (int c = 0; c < 4; ++c) {
      f32x4 v = *(const f32x4*)(src + c * 4);
      #pragma unroll
      for (int e = 0; e < 4; ++e) XmT[(i0 + c * 4 + e) * 128 + m] = v[e];
    }
  }

  f32x4 acc[4][4];
  #pragma unroll
  for (int a = 0; a < 4; ++a)
    #pragma unroll
    for (int b = 0; b < 4; ++b) {
      f32x4 z = {0.f, 0.f, 0.f, 0.f};
      acc[a][b] = z;
    }

  const int wr = w >> 2, wc = w & 3;  // 2x4 wave grid, wave tile 64x64
  const int g = lane >> 4;            // k-slot 0..3 (8 bf16 each)

  int Abase[4];
  #pragma unroll
  for (int fm = 0; fm < 4; ++fm) {
    int m = wr * 64 + fm * 16 + (lane & 15);
    Abase[fm] = m * 64 + ((g ^ ((m >> 1) & 3)) << 4);
  }

  // feat-gen: fg_m = t&127 (row), fg_kh = t>>7 (8-k window, wave-uniform), 8 feats/thread
  const int fg_m = t & 127;
  const int fg_kh = t >> 7;
  const float* xcol = XmT + fg_m;     // XT(i) = xcol[i*128]
  const uint32_t Awr = (uint32_t)(fg_m * 64 + ((fg_kh ^ ((fg_m >> 1) & 3)) << 4));

  const int ks0 = sb * steps_per;
  const int ks1 = (ks0 + steps_per < NSTEPS) ? (ks0 + steps_per) : NSTEPS;

  // ---- featgen for one step into Al[buf] ----
  auto gen_a = [&](int ks, int buf) {
    uint32_t pk[4];
    const int kbase = ks * BK + fg_kh * 8;
    if (USE_IDX) {
      if (kbase >= D + NPAIR) {
        // pure triples: scalarized idx, run-shared pair product
        const u32x4* ip = (const u32x4*)(idxg + kbase);
        u32x4 I0 = ip[0], I1 = ip[1];
        uint32_t prev = 0xFFFFFFFFu;
        float pp = 0.0f;
        float fv[8];
        #pragma unroll
        for (int e = 0; e < 8; ++e) {
          uint32_t uu = __builtin_amdgcn_readfirstlane(e < 4 ? I0[e & 3] : I1[e & 3]);
          uint32_t ij = uu & 0xFFFFu;
          if (ij != prev) {            // scalar branch
            pp = xcol[(uu & 63u) * 128] * xcol[((uu >> 8) & 63u) * 128];
            prev = ij;
          }
          fv[e] = pp * xcol[((uu >> 16) & 63u) * 128];
        }
        #pragma unroll
        for (int c = 0; c < 4; ++c) pk[c] = cvtpk(fv[2 * c], fv[2 * c + 1]);
      } else {
        // singles/pairs region (first 65 steps, sb==0 only): sentinel-guarded
        const u32x4* ip = (const u32x4*)(idxg + kbase);
        u32x4 I0 = ip[0], I1 = ip[1];
        float fv[8];
        #pragma unroll
        for (int e = 0; e < 8; ++e) {
          uint32_t uu = (e < 4) ? I0[e & 3] : I1[e & 3];
          uint32_t ji = (uu >> 8) & 0xFFu, li = uu >> 16;
          float xi = xcol[(uu & 63u) * 128];
          float xj = (ji < 64u) ? xcol[(ji & 63u) * 128] : 1.0f;
          float xl = (li < 64u) ? xcol[(li & 63u) * 128] : 1.0f;
          fv[e] = xi * xj * xl;
        }
        #pragma unroll
        for (int c = 0; c < 4; ++c) pk[c] = cvtpk(fv[2 * c], fv[2 * c + 1]);
      }
    } else {
      int ii, jj, ll;
      unrank(kbase, ii, jj, ll);
      float fv[8];
      #pragma unroll
      for (int h = 0; h < 8; ++h) {
        float xi = xcol[(ii & 63) * 128];
        float xj = (jj < 64) ? xcol[(jj & 63) * 128] : 1.0f;
        float xl = (ll < 64) ? xcol[(ll & 63) * 128] : 1.0f;
        fv[h] = xi * xj * xl;
        if (h < 7) inc_idx(ii, jj, ll);
      }
      #pragma unroll
      for (int c = 0; c < 4; ++c) pk[c] = cvtpk(fv[2 * c], fv[2 * c + 1]);
    }
    u32x4 v0 = {pk[0], pk[1], pk[2], pk[3]};
    *(u32x4*)(&Al[buf][0] + Awr) = v0;
  };

  if constexpr (USE_WT) {
    // ---- B fragments direct from global Wt (L2-resident) ----
    const char* Bp[4];
    #pragma unroll
    for (int fn = 0; fn < 4; ++fn) {
      int row = nb * BN + wc * 64 + fn * 16 + (lane & 15);
      Bp[fn] = Wt + (size_t)row * K2B + ((uint32_t)g << 4);
    }

    // prologue: featgen ks0, publish
    gen_a(ks0, 0);
    __syncthreads();

    int cur = 0;
    for (int ks = ks0; ks < ks1; ++ks) {
      const bool more = (ks + 1 < ks1);
      // issue B-frag loads for THIS step right after the barrier; featgen covers L2 latency
      short8 bv[4];
      {
        const size_t ko = (size_t)(ks * BK) * 2;
        #pragma unroll
        for (int fn = 0; fn < 4; ++fn)
          bv[fn] = *(const short8*)(Bp[fn] + ko);
      }
      if (more) gen_a(ks + 1, cur ^ 1);    // writes Al[cur^1] while we compute on Al[cur]

      __builtin_amdgcn_s_setprio(1);
      short8 av[4];
      #pragma unroll
      for (int fm = 0; fm < 4; ++fm)
        av[fm] = *(const short8*)(&Al[cur][0] + Abase[fm]);
      #pragma unroll
      for (int fm = 0; fm < 4; ++fm)
        #pragma unroll
        for (int fn = 0; fn < 4; ++fn)
          acc[fm][fn] = __builtin_amdgcn_mfma_f32_16x16x32_bf16(av[fm], bv[fn], acc[fm][fn], 0, 0, 0);
      __builtin_amdgcn_s_setprio(0);

      if (more) __syncthreads();           // publish Al[cur^1]
      cur ^= 1;
    }
  } else {
    // ---- fallback: B staged through LDS from W fp32 (r11-verified path) ----
    __shared__ __align__(16) char Bl[2][BN * 64];
    int Bbase[4];
    #pragma unroll
    for (int fn = 0; fn < 4; ++fn) {
      int n = wc * 64 + fn * 16 + (lane & 15);
      Bbase[fn] = n * 64 + ((g ^ ((n >> 1) & 3)) << 4);
    }
    auto stage_b = [&](int ks, int buf) {
      const int k0 = ks * BK;
      #pragma unroll
      for (int i2 = 0; i2 < 2; ++i2) {
        int u = t + i2 * 512;
        int n = u & 255, s = u >> 8;
        const float* wp = W + (size_t)(k0 + s * 8) * NOUT + nb * BN + n;
        float f[8];
        #pragma unroll
        for (int e = 0; e < 8; ++e) f[e] = wp[(size_t)e * NOUT];
        u32x4 v = {cvtpk(f[0], f[1]), cvtpk(f[2], f[3]),
                   cvtpk(f[4], f[5]), cvtpk(f[6], f[7])};
        *(u32x4*)(&Bl[buf][0] + n * 64 + ((s ^ ((n >> 1) & 3)) << 4)) = v;
      }
    };

    stage_b(ks0, 0);
    gen_a(ks0, 0);
    __syncthreads();

    int cur = 0;
    for (int ks = ks0; ks < ks1; ++ks) {
      const bool more = (ks + 1 < ks1);
      if (more) { stage_b(ks + 1, cur ^ 1); gen_a(ks + 1, cur ^ 1); }

      __builtin_amdgcn_s_setprio(1);
      short8 av[4], bv[4];
      #pragma unroll
      for (int fm = 0; fm < 4; ++fm)
        av[fm] = *(const short8*)(&Al[cur][0] + Abase[fm]);
      #pragma unroll
      for (int fn = 0; fn < 4; ++fn)
        bv[fn] = *(const short8*)(&Bl[cur][0] + Bbase[fn]);
      #pragma unroll
      for (int fm = 0; fm < 4; ++fm)
        #pragma unroll
        for (int fn = 0; fn < 4; ++fn)
          acc[fm][fn] = __builtin_amdgcn_mfma_f32_16x16x32_bf16(av[fm], bv[fn], acc[fm][fn], 0, 0, 0);
      __builtin_amdgcn_s_setprio(0);

      if (more) __syncthreads();
      cur ^= 1;
    }
  }

  // ---- store partials. D layout: row=(lane>>4)*4+r, col=lane&15 (m89-verified) ----
  #pragma unroll
  for (int fm = 0; fm < 4; ++fm) {
    int rbase = mb * BM + wr * 64 + fm * 16 + ((lane >> 4) << 2);
    #pragma unroll
    for (int fn = 0; fn < 4; ++fn) {
      int col = nb * BN + wc * 64 + fn * 16 + (lane & 15);
      float* dst = part + ((size_t)sb * MROWS + rbase) * NOUT + col;
      #pragma unroll
      for (int r = 0; r < 4; ++r) dst[(size_t)r * NOUT] = acc[fm][fn][r];
    }
  }
}

// ---------------- kernel 4: sum partials + bias + LayerNorm + ReLU ----------------
// no __restrict__ on part/out: alias when S==1.
__global__ void ln_k(const float* part, int S,
                     const float* __restrict__ bias, const float* __restrict__ gamma,
                     const float* __restrict__ beta, float* out) {
  int row = blockIdx.x;
  int t = threadIdx.x;            // 256 threads, 2 cols each
  float v[2];
  #pragma unroll
  for (int q = 0; q < 2; ++q) {
    int c = t + q * 256;
    float s = bias[c];
    for (int sbi = 0; sbi < S; ++sbi)
      s += part[((size_t)sbi * MROWS + row) * NOUT + c];
    v[q] = s;
  }
  float sum = v[0] + v[1];
  float sq = v[0] * v[0] + v[1] * v[1];
  #pragma unroll
  for (int off = 32; off > 0; off >>= 1) {
    sum += __shfl_xor(sum, off, 64);
    sq  += __shfl_xor(sq, off, 64);
  }
  __shared__ float red[8];
  int wv = t >> 6;
  if ((t & 63) == 0) { red[wv] = sum; red[4 + wv] = sq; }
  __syncthreads();
  sum = red[0] + red[1] + red[2] + red[3];
  sq  = red[4] + red[5] + red[6] + red[7];
  float mu = sum * (1.0f / NOUT);
  float var = sq * (1.0f / NOUT) - mu * mu;
  float rs = rsqrtf(var + 1e-5f);
  #pragma unroll
  for (int q = 0; q < 2; ++q) {
    int c = t + q * 256;
    float hn = (v[q] - mu) * rs * gamma[c] + beta[c];
    out[(size_t)row * NOUT + c] = fmaxf(hn, 0.0f);
  }
}

extern "C" void kernel_launch(void* const* d_in, const int* in_sizes, int n_in,
                              void* d_out, int out_size, void* d_ws, size_t ws_size,
                              hipStream_t stream) {
  const float* x     = (const float*)d_in[0];
  const float* W     = (const float*)d_in[1];
  const float* bias  = (const float*)d_in[2];
  const float* gamma = (const float*)d_in[3];
  const float* beta  = (const float*)d_in[4];
  float* out = (float*)d_out;
  (void)in_sizes; (void)n_in; (void)out_size;

  const size_t IDXB = 262144;                        // >= KTOT*4
  const size_t WTB  = (size_t)NOUT * K2B;            // 44,793,856
  const size_t PART = (size_t)MROWS * NOUT * sizeof(float);  // 8 MB

  char* base = (char*)d_ws;
  uint32_t* idx = (uint32_t*)base;
  char* Wt = base + IDXB;

  const bool has_idx = ws_size >= IDXB;
  bool use_wt = false;
  int S = 1, Slog = 0;
  if (ws_size >= IDXB + WTB + 8 * PART)      { use_wt = true;  S = 8; Slog = 3; }
  else if (ws_size >= IDXB + 8 * PART)       { use_wt = false; S = 8; Slog = 3; }
  else if (ws_size >= IDXB + WTB + 4 * PART) { use_wt = true;  S = 4; Slog = 2; }
  else if (ws_size >= IDXB + 4 * PART)       { use_wt = false; S = 4; Slog = 2; }
  else if (ws_size >= IDXB + WTB + 2 * PART) { use_wt = true;  S = 2; Slog = 1; }
  else if (ws_size >= IDXB + 2 * PART)       { use_wt = false; S = 2; Slog = 1; }
  else if (ws_size >= IDXB + WTB)            { use_wt = true;  S = 1; Slog = 0; }

  float* part = out;   // S==1: h accumulates straight into d_out (ln in place)
  if (S > 1) part = (float*)(base + IDXB + (use_wt ? WTB : 0));

  int steps_per = (NSTEPS + S - 1) / S;     // 171 at S=8
  int grid = 32 * (NOUT / BN) * S;
  int swz = (grid == 512) ? 1 : 0;

  if (has_idx) build_idx_k<<<(KTOT + 255) / 256, 256, 0, stream>>>(idx);
  if (use_wt)  wtrans_k<<<dim3((KTOT + 63) / 64, 8), 256, 0, stream>>>(W, Wt);

  if (use_wt)
    gemm_k<1, 1><<<grid, 512, 0, stream>>>(x, W, Wt, idx, part, S, Slog, steps_per, swz);
  else if (has_idx)
    gemm_k<0, 1><<<grid, 512, 0, stream>>>(x, W, Wt, idx, part, S, Slog, steps_per, swz);
  else
    gemm_k<0, 0><<<grid, 512, 0, stream>>>(x, W, Wt, nullptr, part, S, Slog, steps_per, swz);

  ln_k<<<MROWS, 256, 0, stream>>>(part, S, bias, gamma, beta, out);
}